// Round 4
// baseline (275.156 us; speedup 1.0000x reference)
//
#include <hip/hip_runtime.h>
#include <cstdint>
#include <cstddef>

// Problem constants
#define NB   32    // query batch
#define NSUP 25    // support images
#define KCLS 5     // classes
#define NC   512   // input channels
#define ND   128   // dk = dv
#define NP   196   // h*w
#define JS   208   // per-support padded row/col count (13*16)
#define NIMG 57    // 32 query + 25 support
#define SHIFT 8.0f // fixed logit shift (softmax-invariant overflow guard)
#define NA4 (NIMG*JS*ND/4)   // 379392 fixup quads per domain

typedef __attribute__((ext_vector_type(8))) short short8;   // 8 x bf16
typedef __attribute__((ext_vector_type(4))) float floatx4;  // MFMA C/D

struct alignas(8) us4 { uint16_t x, y, z, w; };

__device__ inline short f2bf(float x) {
  union { float f; uint32_t u; } v; v.f = x;
  uint32_t r = (v.u + 0x7FFFu + ((v.u >> 16) & 1u)) >> 16;  // RNE
  return (short)(r & 0xFFFFu);
}
__device__ inline float bf2f(short h) {
  union { uint32_t u; float f; } v; v.u = ((uint32_t)(uint16_t)h) << 16;
  return v.f;
}
__device__ inline float bperm(int byteAddr, float v) {
  return __int_as_float(__builtin_amdgcn_ds_bpermute(byteAddr, __float_as_int(v)));
}

// ---------------------------------------------------------------------------
// Kernel 0: fp32 -> bf16 hi/lo convert + transpose.
//   Xhi/Xlo[img][pp:208][c:512] (c-contig; pad rows = copy of row 195)
//   Whi/Wlo[mat][d:128][c:512]
// grid = 57*16 + 2 = 914 blocks x 256 threads.
// ---------------------------------------------------------------------------
__global__ __launch_bounds__(256) void conv_kernel(
    const float* __restrict__ supp, const float* __restrict__ qry,
    const float* __restrict__ Wqk, const float* __restrict__ Wv,
    uint16_t* __restrict__ Xhi, uint16_t* __restrict__ Xlo,
    uint16_t* __restrict__ Whi, uint16_t* __restrict__ Wlo)
{
  const int bx = blockIdx.x, tid = (int)threadIdx.x;
  if (bx >= 912) {                    // W conversion
    const int mat = bx - 912;
    const float* __restrict__ W = mat ? Wv : Wqk;
    uint16_t* dh = Whi + (size_t)mat * ND * NC;
    uint16_t* dl = Wlo + (size_t)mat * ND * NC;
    for (int i = tid; i < ND * NC; i += 256) {
      const float x = W[i];
      const short h = f2bf(x);
      dh[i] = (uint16_t)h;
      dl[i] = (uint16_t)f2bf(x - bf2f(h));
    }
    return;
  }
  __shared__ float lds[32 * 209];
  const int img = bx >> 4, c0 = (bx & 15) * 32;
  const float* __restrict__ X = (img < NB)
      ? (qry  + (size_t)img * NC * NP)
      : (supp + (size_t)(img - NB) * NC * NP);
  for (int idx = tid; idx < 32 * JS; idx += 256) {   // read [c][p] coalesced
    const int cc = idx / JS, pp = idx - cc * JS;
    lds[cc * 209 + pp] = X[(c0 + cc) * NP + (pp < NP ? pp : NP - 1)];
  }
  __syncthreads();
  for (int idx = tid; idx < 32 * JS; idx += 256) {   // write [p][c] coalesced
    const int cc = idx & 31, pp = idx >> 5;
    const float x = lds[cc * 209 + pp];
    const short h = f2bf(x);
    const size_t o = ((size_t)img * JS + pp) * NC + c0 + cc;
    Xhi[o] = (uint16_t)h;
    Xlo[o] = (uint16_t)f2bf(x - bf2f(h));
  }
}

// ---------------------------------------------------------------------------
// Kernel 1: merged projection GEMM, bf16 MFMA, K-split 2-way.
// One wave per (img, p-tile16, K-half): grid = 57*13*2 = 1482 x 64.
// X fragment is SHARED between both products (A for QK, B for V — identical
// [lane&15][k] layout):
//   QK (1-term):  A=X(m=p), B=Wqk(n=d)  -> Pqk[part][img][p:208][d]
//   V  (3-term):  A=Wv(m=d), B=X(n=p)   -> Pv [part][img][d][p:208] (transposed!)
// ---------------------------------------------------------------------------
__global__ __launch_bounds__(64, 3) void gemm_kernel(
    const uint16_t* __restrict__ Xhi, const uint16_t* __restrict__ Xlo,
    const uint16_t* __restrict__ Whi, const uint16_t* __restrict__ Wlo,
    float* __restrict__ Pqk, float* __restrict__ Pv)
{
  const int bx = blockIdx.x;
  const int part = bx & 1, idx = bx >> 1;
  const int t16 = idx % 13, img = idx / 13;
  const int c0 = part * 256;
  const int lane = (int)threadIdx.x, ln = lane & 15, q = lane >> 4;

  const size_t xrow = ((size_t)img * JS + t16 * 16 + ln) * NC + c0 + q * 8;
  const size_t wq   = (size_t)ln * NC + c0 + q * 8;          // + nt*16*NC
  const size_t wv   = (size_t)ND * NC + wq;                  // W_v base

  floatx4 aQ[8], aV[8];
  #pragma unroll
  for (int nt = 0; nt < 8; ++nt) {
    aQ[nt] = (floatx4){0.f, 0.f, 0.f, 0.f};
    aV[nt] = (floatx4){0.f, 0.f, 0.f, 0.f};
  }

  for (int ks = 0; ks < 8; ++ks) {
    const int co = ks * 32;
    const short8 xh = *(const short8*)(Xhi + xrow + co);
    const short8 xl = *(const short8*)(Xlo + xrow + co);
    #pragma unroll
    for (int nt = 0; nt < 8; ++nt) {
      const short8 wqh = *(const short8*)(Whi + wq + (size_t)nt * 16 * NC + co);
      aQ[nt] = __builtin_amdgcn_mfma_f32_16x16x32_bf16(xh, wqh, aQ[nt], 0, 0, 0);
    }
    #pragma unroll
    for (int nt = 0; nt < 8; ++nt) {
      const short8 wvh = *(const short8*)(Whi + wv + (size_t)nt * 16 * NC + co);
      const short8 wvl = *(const short8*)(Wlo + wv + (size_t)nt * 16 * NC + co);
      aV[nt] = __builtin_amdgcn_mfma_f32_16x16x32_bf16(wvh, xh, aV[nt], 0, 0, 0);
      aV[nt] = __builtin_amdgcn_mfma_f32_16x16x32_bf16(wvh, xl, aV[nt], 0, 0, 0);
      aV[nt] = __builtin_amdgcn_mfma_f32_16x16x32_bf16(wvl, xh, aV[nt], 0, 0, 0);
    }
  }

  // QK: D row = p = t16*16+q*4+rr, col = d = nt*16+ln
  float* dq = Pqk + ((size_t)part * NIMG + img) * JS * ND;
  #pragma unroll
  for (int nt = 0; nt < 8; ++nt)
    #pragma unroll
    for (int rr = 0; rr < 4; ++rr)
      dq[(size_t)(t16 * 16 + q * 4 + rr) * ND + nt * 16 + ln] = aQ[nt][rr];
  // V: D row = d = nt*16+q*4+rr, col = p = t16*16+ln  (already transposed)
  float* dv = Pv + ((size_t)part * NIMG + img) * ND * JS;
  #pragma unroll
  for (int nt = 0; nt < 8; ++nt)
    #pragma unroll
    for (int rr = 0; rr < 4; ++rr)
      dv[(size_t)(nt * 16 + q * 4 + rr) * JS + t16 * 16 + ln] = aV[nt][rr];
}

// ---------------------------------------------------------------------------
// Kernel 2: K-split fixup (purely elementwise now). Sums 2 fp32 partials,
// emits bf16 Qt/Kt/Vt and fp32 outVq. grid = 2964 x 256 (float4/thread).
// ---------------------------------------------------------------------------
__global__ __launch_bounds__(256) void fix_kernel(
    const float* __restrict__ Pqk, const float* __restrict__ Pv,
    uint16_t* __restrict__ Qt, uint16_t* __restrict__ Kt,
    uint16_t* __restrict__ Vt, float* __restrict__ outVq)
{
  const int i = blockIdx.x * 256 + (int)threadIdx.x;
  const size_t SP = (size_t)NIMG * JS * ND;   // per-part stride (both domains)
  if (i < NA4) {
    const size_t e = (size_t)i * 4;
    floatx4 s = *(const floatx4*)(Pqk + e);
    s += *(const floatx4*)(Pqk + e + SP);
    const int ei = (int)e;
    const int img = ei / (JS * ND), rem = ei % (JS * ND);
    const int p = rem / ND, d0 = rem % ND;
    us4 pk; pk.x = (uint16_t)f2bf(s[0]); pk.y = (uint16_t)f2bf(s[1]);
    pk.z = (uint16_t)f2bf(s[2]); pk.w = (uint16_t)f2bf(s[3]);
    if (img < NB) {
      if (p < NP) *(us4*)&Qt[((size_t)img * NP + p) * ND + d0] = pk;
    } else {
      *(us4*)&Kt[((size_t)(img - NB) * JS + p) * ND + d0] = pk;
    }
  } else {
    const size_t e = (size_t)(i - NA4) * 4;
    floatx4 s = *(const floatx4*)(Pv + e);
    s += *(const floatx4*)(Pv + e + SP);
    const int ei = (int)e;
    const int img = ei / (ND * JS), rem = ei % (ND * JS);
    const int d = rem / JS, pp = rem % JS;
    if (img < NB) {
      if (pp < NP) *(floatx4*)&outVq[((size_t)img * ND + d) * NP + pp] = s;
    } else {
      us4 pk; pk.x = (uint16_t)f2bf(s[0]); pk.y = (uint16_t)f2bf(s[1]);
      pk.z = (uint16_t)f2bf(s[2]); pk.w = (uint16_t)f2bf(s[3]);
      *(us4*)&Vt[((size_t)(img - NB) * ND + d) * JS + pp] = pk;
    }
  }
}

// ---------------------------------------------------------------------------
// Kernel 3: per-class masked attention. Block = (b, kc, 64-row p-group),
// 4 waves p-split; all waves walk the SAME chunk sequence (L1 K/V sharing).
// No LDS buffers, no barriers, no cross-wave merge.
// QK computed as S^T (A=K, B=Q) so the D->B-operand transform is a uniform
// in-register ds_bpermute: src lane = ln+32*(q&1)(+16), reg = x&3, tile = q>>1.
// grid = 32*5*4 = 640 blocks x 256 threads.
// ---------------------------------------------------------------------------
__global__ __launch_bounds__(256, 3) void attn_kernel(
    const uint16_t* __restrict__ Qt, const uint16_t* __restrict__ Kt,
    const uint16_t* __restrict__ Vt, const int* __restrict__ labels,
    float* __restrict__ out)
{
  const int bx = blockIdx.x;
  const int b = bx / 20, rem = bx % 20, kc = rem / 4, pg = rem % 4;
  const int tid = (int)threadIdx.x;
  const int w = tid >> 6, lane = tid & 63, ln = lane & 15, q = lane >> 4;
  const int p0 = pg * 64 + w * 16;

  // class-support list packed in a register (6 bits per slot) via ballot
  const int myl = (lane < NSUP) ? labels[lane] : -1;
  unsigned long long m = __ballot(myl == kc);
  int clsPack = 0;
  #pragma unroll
  for (int s = 0; s < 5; ++s) {
    const int n = (m != 0ull) ? (int)__builtin_ctzll(m) : 0;
    clsPack |= n << (6 * s);
    m &= (m - 1);
  }

  // Q B-fragments (resident): B[n=p][k=d]
  short8 aq[4];
  {
    int p = p0 + ln; if (p > NP - 1) p = NP - 1;
    const uint16_t* base = Qt + ((size_t)b * NP + p) * ND + q * 8;
    #pragma unroll
    for (int ks = 0; ks < 4; ++ks) aq[ks] = *(const short8*)(base + ks * 32);
  }

  floatx4 acc[8];
  #pragma unroll
  for (int dt = 0; dt < 8; ++dt) acc[dt] = (floatx4){0.f, 0.f, 0.f, 0.f};
  float Ssum = 0.f;

  for (int it = 0; it < 33; ++it) {
    // --- V A-frags (independent; issue early) ---
    const int cc = it * 32 + q * 8;
    int s2 = cc / JS, j2 = cc - s2 * JS;
    if (s2 > 4) { s2 = 4; j2 = 192; }          // pad tile: weights are 0
    const int n2 = (clsPack >> (6 * s2)) & 63;
    short8 av[8];
    #pragma unroll
    for (int dt = 0; dt < 8; ++dt)
      av[dt] = *(const short8*)(Vt + ((size_t)n2 * ND + dt * 16 + ln) * JS + j2);

    // --- K A-frags for the 2 16-col tiles ---
    short8 bk[2][4];
    int jb[2]; bool tval[2];
    #pragma unroll
    for (int t = 0; t < 2; ++t) {
      const int tile16 = it * 2 + t;
      int s = tile16 / 13;
      const int j0 = (tile16 - s * 13) * 16;
      tval[t] = (s < 5); jb[t] = j0;
      if (s > 4) s = 4;
      const int n = (clsPack >> (6 * s)) & 63;
      const uint16_t* kp = Kt + ((size_t)n * JS + j0 + ln) * ND + q * 8;
      #pragma unroll
      for (int ks = 0; ks < 4; ++ks) bk[t][ks] = *(const short8*)(kp + ks * 32);
    }

    // --- QK as S^T (A=K m=j, B=Q n=p) + exp ---
    floatx4 e0, e1;
    #pragma unroll
    for (int t = 0; t < 2; ++t) {
      floatx4 d4 = {0.f, 0.f, 0.f, 0.f};
      #pragma unroll
      for (int ks = 0; ks < 4; ++ks)
        d4 = __builtin_amdgcn_mfma_f32_16x16x32_bf16(bk[t][ks], aq[ks], d4, 0, 0, 0);
      floatx4 ev;
      #pragma unroll
      for (int r = 0; r < 4; ++r) {
        const int j = jb[t] + q * 4 + r;
        const float e = (tval[t] && j < NP) ? __expf(d4[r] - SHIFT) : 0.f;
        ev[r] = e;
        Ssum += e;
      }
      if (t == 0) e0 = ev; else e1 = ev;
    }

    // --- D-layout -> B-operand transform via ds_bpermute ---
    const int alo = (ln + ((q & 1) << 5)) << 2;   // byte addr of src lane
    const bool hiTile = (q >= 2);                  // dest tile = q>>1
    short8 bp;
    #pragma unroll
    for (int r = 0; r < 4; ++r) {
      const float lo0 = bperm(alo, e0[r]);
      const float lo1 = bperm(alo, e1[r]);
      const float hi0 = bperm(alo + 64, e0[r]);
      const float hi1 = bperm(alo + 64, e1[r]);
      bp[r]     = f2bf(hiTile ? lo1 : lo0);
      bp[4 + r] = f2bf(hiTile ? hi1 : hi0);
    }

    // --- PV: A=V (m=d), B=P (n=p) -> D[d][p] ---
    #pragma unroll
    for (int dt = 0; dt < 8; ++dt)
      acc[dt] = __builtin_amdgcn_mfma_f32_16x16x32_bf16(av[dt], bp, acc[dt], 0, 0, 0);
  }

  // --- normalize (per-lane: p = p0 + ln) and store ---
  Ssum += __shfl_xor(Ssum, 16);
  Ssum += __shfl_xor(Ssum, 32);
  const float invS = 1.f / Ssum;
  const int pp = p0 + ln;
  if (pp < NP) {
    float* ob = out + ((size_t)(b * KCLS + kc) * ND + q * 4) * NP + pp;
    #pragma unroll
    for (int dt = 0; dt < 8; ++dt)
      #pragma unroll
      for (int rr = 0; rr < 4; ++rr)
        ob[(size_t)(dt * 16 + rr) * NP] = acc[dt][rr] * invS;
  }
}

// ---------------------------------------------------------------------------
extern "C" void kernel_launch(void* const* d_in, const int* in_sizes, int n_in,
                              void* d_out, int out_size, void* d_ws, size_t ws_size,
                              hipStream_t stream) {
  const float* supp   = (const float*)d_in[0];
  const float* qry    = (const float*)d_in[1];
  const int*   labels = (const int*)d_in[2];
  const float* Wqk    = (const float*)d_in[3];
  const float* Wv     = (const float*)d_in[4];
  float* out = (float*)d_out;

  // ws layout (~53.4 MB)
  uint16_t* Xhi = (uint16_t*)d_ws;
  uint16_t* Xlo = Xhi + (size_t)NIMG * JS * NC;
  uint16_t* Whi = Xlo + (size_t)NIMG * JS * NC;
  uint16_t* Wlo = Whi + (size_t)2 * ND * NC;
  uint16_t* Qt  = Wlo + (size_t)2 * ND * NC;        // [32][196][128]
  uint16_t* Kt  = Qt  + (size_t)NB * NP * ND;       // [25][208][128]
  uint16_t* Vt  = Kt  + (size_t)NSUP * JS * ND;     // [25][128][208]
  float* Pqk = (float*)(Vt + (size_t)NSUP * ND * JS);
  float* Pv  = Pqk + (size_t)2 * NIMG * JS * ND;
  float* outVq = out + (size_t)NB * KCLS * ND * NP; // query_v_flat region

  conv_kernel<<<914, 256, 0, stream>>>(supp, qry, Wqk, Wv, Xhi, Xlo, Whi, Wlo);
  gemm_kernel<<<1482, 64, 0, stream>>>(Xhi, Xlo, Whi, Wlo, Pqk, Pv);
  fix_kernel<<<2964, 256, 0, stream>>>(Pqk, Pv, Qt, Kt, Vt, outVq);
  attn_kernel<<<640, 256, 0, stream>>>(Qt, Kt, Vt, labels, out);
}

// Round 6
// 226.117 us; speedup vs baseline: 1.2169x; 1.2169x over previous
//
#include <hip/hip_runtime.h>
#include <cstdint>
#include <cstddef>

// Problem constants
#define NB   32    // query batch
#define NSUP 25    // support images
#define KCLS 5     // classes
#define NC   512   // input channels
#define ND   128   // dk = dv
#define NP   196   // h*w
#define JS   208   // per-support padded spatial (13*16)
#define NIMG 57    // 32 query + 25 support
#define SHIFT 8.0f // fixed logit shift (softmax-invariant overflow guard)

typedef __attribute__((ext_vector_type(8))) short short8;   // 8 x bf16 (4 VGPRs)
typedef __attribute__((ext_vector_type(4))) float floatx4;  // MFMA C/D

__device__ inline short f2bf(float x) {
  union { float f; uint32_t u; } v; v.f = x;
  uint32_t r = (v.u + 0x7FFFu + ((v.u >> 16) & 1u)) >> 16;  // RNE
  return (short)(r & 0xFFFFu);
}
__device__ inline float bf2f(short h) {
  union { uint32_t u; float f; } v; v.u = ((uint32_t)(uint16_t)h) << 16;
  return v.f;
}
__device__ inline uint32_t pk2(float a, float b) {
  return (uint32_t)(uint16_t)f2bf(a) | ((uint32_t)(uint16_t)f2bf(b) << 16);
}

// ---------------------------------------------------------------------------
// Kernel 0: fp32 -> bf16 hi/lo convert + transpose.  (verbatim R3/R4, passed)
//   Xhi/Xlo[img][pp:208][c:512] (c-contig; pad rows = copy of row 195)
//   Whi/Wlo[mat][d:128][c:512]
// grid = 57*16 + 2 = 914 blocks x 256 threads.
// ---------------------------------------------------------------------------
__global__ __launch_bounds__(256) void conv_kernel(
    const float* __restrict__ supp, const float* __restrict__ qry,
    const float* __restrict__ Wqk, const float* __restrict__ Wv,
    uint16_t* __restrict__ Xhi, uint16_t* __restrict__ Xlo,
    uint16_t* __restrict__ Whi, uint16_t* __restrict__ Wlo)
{
  const int bx = blockIdx.x, tid = (int)threadIdx.x;
  if (bx >= 912) {                    // W conversion
    const int mat = bx - 912;
    const float* __restrict__ W = mat ? Wv : Wqk;
    uint16_t* dh = Whi + (size_t)mat * ND * NC;
    uint16_t* dl = Wlo + (size_t)mat * ND * NC;
    for (int i = tid; i < ND * NC; i += 256) {
      const float x = W[i];
      const short h = f2bf(x);
      dh[i] = (uint16_t)h;
      dl[i] = (uint16_t)f2bf(x - bf2f(h));
    }
    return;
  }
  __shared__ float lds[32 * 209];
  const int img = bx >> 4, c0 = (bx & 15) * 32;
  const float* __restrict__ X = (img < NB)
      ? (qry  + (size_t)img * NC * NP)
      : (supp + (size_t)(img - NB) * NC * NP);
  for (int idx = tid; idx < 32 * JS; idx += 256) {   // read [c][p] coalesced
    const int cc = idx / JS, pp = idx - cc * JS;
    lds[cc * 209 + pp] = X[(c0 + cc) * NP + (pp < NP ? pp : NP - 1)];
  }
  __syncthreads();
  for (int idx = tid; idx < 32 * JS; idx += 256) {   // write [p][c] coalesced
    const int cc = idx & 31, pp = idx >> 5;
    const float x = lds[cc * 209 + pp];
    const short h = f2bf(x);
    const size_t o = ((size_t)img * JS + pp) * NC + c0 + cc;
    Xhi[o] = (uint16_t)h;
    Xlo[o] = (uint16_t)f2bf(x - bf2f(h));
  }
}

// ---------------------------------------------------------------------------
// Kernel 1: merged projection GEMM, full K=512 per wave (no split-K/fixup).
// One wave per (img, p-tile16, d-half64): grid = 57*13*2 = 1482 x 64.
//   QK (1-term):  A=X(m=p), B=Wqk(n=d)  -> bf16 Qt[b][p<196][d] / Kt[n][p:208][d]
//   V  (3-term):  A=Wv(m=d), B=X(n=p)   -> bf16 Vt[n][d][p:208] / fp32 outVq[b][d][p]
// All components individually validated in R2/R4 passing rounds.
// ---------------------------------------------------------------------------
__global__ __launch_bounds__(64, 4) void gemm_kernel(
    const uint16_t* __restrict__ Xhi, const uint16_t* __restrict__ Xlo,
    const uint16_t* __restrict__ Whi, const uint16_t* __restrict__ Wlo,
    uint16_t* __restrict__ Qt, uint16_t* __restrict__ Kt,
    uint16_t* __restrict__ Vt, float* __restrict__ outVq)
{
  const int bx = blockIdx.x;
  const int half = bx & 1, idx = bx >> 1;
  const int t16 = idx % 13, img = idx / 13;
  const int lane = (int)threadIdx.x, ln = lane & 15, q = lane >> 4;
  const int d0 = half * 64;

  const size_t xrow = ((size_t)img * JS + t16 * 16 + ln) * NC + q * 8;
  floatx4 aQ[4], aV[4];
  #pragma unroll
  for (int nt = 0; nt < 4; ++nt) {
    aQ[nt] = (floatx4){0.f, 0.f, 0.f, 0.f};
    aV[nt] = (floatx4){0.f, 0.f, 0.f, 0.f};
  }

  for (int ks = 0; ks < 16; ++ks) {
    const int co = ks * 32;
    const short8 xh = *(const short8*)(Xhi + xrow + co);
    const short8 xl = *(const short8*)(Xlo + xrow + co);
    #pragma unroll
    for (int nt = 0; nt < 4; ++nt) {
      const size_t wr = (size_t)(d0 + nt * 16 + ln) * NC + co + q * 8;
      const short8 wqh = *(const short8*)(Whi + wr);
      aQ[nt] = __builtin_amdgcn_mfma_f32_16x16x32_bf16(xh, wqh, aQ[nt], 0, 0, 0);
      const short8 wvh = *(const short8*)(Whi + (size_t)ND * NC + wr);
      const short8 wvl = *(const short8*)(Wlo + (size_t)ND * NC + wr);
      aV[nt] = __builtin_amdgcn_mfma_f32_16x16x32_bf16(wvh, xh, aV[nt], 0, 0, 0);
      aV[nt] = __builtin_amdgcn_mfma_f32_16x16x32_bf16(wvh, xl, aV[nt], 0, 0, 0);
      aV[nt] = __builtin_amdgcn_mfma_f32_16x16x32_bf16(wvl, xh, aV[nt], 0, 0, 0);
    }
  }

  // QK: D row = p = t16*16+q*4+rr, col = d = d0+nt*16+ln
  if (img < NB) {
    #pragma unroll
    for (int nt = 0; nt < 4; ++nt)
      #pragma unroll
      for (int rr = 0; rr < 4; ++rr) {
        const int p = t16 * 16 + q * 4 + rr;
        if (p < NP)
          Qt[((size_t)img * NP + p) * ND + d0 + nt * 16 + ln] = (uint16_t)f2bf(aQ[nt][rr]);
      }
  } else {
    const int n = img - NB;
    #pragma unroll
    for (int nt = 0; nt < 4; ++nt)
      #pragma unroll
      for (int rr = 0; rr < 4; ++rr) {
        const int p = t16 * 16 + q * 4 + rr;        // 0..207, pads masked in attn
        Kt[((size_t)n * JS + p) * ND + d0 + nt * 16 + ln] = (uint16_t)f2bf(aQ[nt][rr]);
      }
  }
  // V: D row = d = d0+nt*16+q*4+rr, col = p = t16*16+ln
  const int p = t16 * 16 + ln;
  if (img < NB) {
    if (p < NP) {
      #pragma unroll
      for (int nt = 0; nt < 4; ++nt)
        #pragma unroll
        for (int rr = 0; rr < 4; ++rr)
          outVq[((size_t)img * ND + d0 + nt * 16 + q * 4 + rr) * NP + p] = aV[nt][rr];
    }
  } else {
    const int n = img - NB;
    #pragma unroll
    for (int nt = 0; nt < 4; ++nt)
      #pragma unroll
      for (int rr = 0; rr < 4; ++rr)
        Vt[((size_t)n * ND + d0 + nt * 16 + q * 4 + rr) * JS + p] = (uint16_t)f2bf(aV[nt][rr]);
  }
}

// ---------------------------------------------------------------------------
// Kernel 2: per-class masked attention, 16x16x32 MFMA (verified layouts).
// Block = (b-pair, kc, p-tile16), 4 waves j-split; each wave serves BOTH
// batches of the pair from the same K/V fragments (VMEM per MFMA halved).
// Transform = R4's verified bpermute quad-exchange (packed-pair variant).
// grid = 16*5*13 = 1040 blocks x 256 threads.
// ---------------------------------------------------------------------------
__global__ __launch_bounds__(256, 2) void attn_kernel(
    const uint16_t* __restrict__ Qt, const uint16_t* __restrict__ Kt,
    const uint16_t* __restrict__ Vt, const int* __restrict__ labels,
    float* __restrict__ out)
{
  __shared__ float mergeAcc[4][4][256];   // 16 KB merge buffer
  __shared__ float sS[2][4][16];

  const int bx = blockIdx.x;              // 1040 = 16*5*13
  const int pt = bx % 13;
  const int rem = bx / 13;                // 80 = 16*5
  const int kc = rem % KCLS;
  const int b0 = (rem / KCLS) * 2;        // batch pair base
  const int p0 = pt * 16;
  const int tid = (int)threadIdx.x;
  const int w = tid >> 6, lane = tid & 63, ln = lane & 15, q = lane >> 4;

  // class-support list packed in a register (6 bits/slot) via ballot
  const int myl = (lane < NSUP) ? labels[lane] : -1;
  unsigned long long m = __ballot(myl == kc);
  int clsPack = 0;
  #pragma unroll
  for (int s = 0; s < 5; ++s) {
    const int n = (m != 0ull) ? (int)__builtin_ctzll(m) : 0;
    clsPack |= n << (6 * s);
    m &= (m - 1);
  }

  // Q B-frags (resident, per batch): B[n=p][k=d]
  short8 aq[2][4];
  #pragma unroll
  for (int bb = 0; bb < 2; ++bb) {
    int p = p0 + ln; if (p > NP - 1) p = NP - 1;
    const uint16_t* base = Qt + ((size_t)(b0 + bb) * NP + p) * ND + q * 8;
    #pragma unroll
    for (int ks = 0; ks < 4; ++ks) aq[bb][ks] = *(const short8*)(base + ks * 32);
  }

  floatx4 acc[2][8];
  #pragma unroll
  for (int bb = 0; bb < 2; ++bb)
    #pragma unroll
    for (int dt = 0; dt < 8; ++dt) acc[bb][dt] = (floatx4){0.f, 0.f, 0.f, 0.f};
  float Ssum[2] = {0.f, 0.f};

  const int alo = (ln + ((q & 1) << 5)) << 2;  // bpermute byte addr (R4-verified)
  const bool hiTile = (q >= 2);

  for (int it = w; it < 33; it += 4) {         // this wave's 32-col chunks
    // --- V B-frags (shared across batches): B[n=d][k=j] ---
    const int cc = it * 32 + q * 8;
    int s2 = cc / JS, j2 = cc - s2 * JS;
    if (s2 > 4) { s2 = 4; j2 = 192; }          // pad region: weights are 0
    const int n2 = (clsPack >> (6 * s2)) & 63;
    short8 av[8];
    #pragma unroll
    for (int dt = 0; dt < 8; ++dt)
      av[dt] = *(const short8*)(Vt + ((size_t)n2 * ND + dt * 16 + ln) * JS + j2);

    // --- K A-frags (shared): A[m=j][k=d], per 16-col tile ---
    short8 bk[2][4];
    int jb[2]; bool tval[2];
    #pragma unroll
    for (int t = 0; t < 2; ++t) {
      const int tile16 = it * 2 + t;
      int s = tile16 / 13;
      const int j0 = (tile16 - s * 13) * 16;
      tval[t] = (s < 5); jb[t] = j0;
      if (s > 4) s = 4;
      const int n = (clsPack >> (6 * s)) & 63;
      const uint16_t* kp = Kt + ((size_t)n * JS + j0 + ln) * ND + q * 8;
      #pragma unroll
      for (int ks = 0; ks < 4; ++ks) bk[t][ks] = *(const short8*)(kp + ks * 32);
    }

    // --- per batch: QK as S^T, exp, transform, PV ---
    #pragma unroll
    for (int bb = 0; bb < 2; ++bb) {
      floatx4 e0, e1;
      #pragma unroll
      for (int t = 0; t < 2; ++t) {
        floatx4 d4 = {0.f, 0.f, 0.f, 0.f};
        #pragma unroll
        for (int ks = 0; ks < 4; ++ks)
          d4 = __builtin_amdgcn_mfma_f32_16x16x32_bf16(bk[t][ks], aq[bb][ks], d4, 0, 0, 0);
        floatx4 ev;
        #pragma unroll
        for (int r = 0; r < 4; ++r) {
          const int j = jb[t] + q * 4 + r;
          const float e = (tval[t] && j < NP) ? __expf(d4[r] - SHIFT) : 0.f;
          ev[r] = e;
          Ssum[bb] += e;
        }
        if (t == 0) e0 = ev; else e1 = ev;
      }

      // D-layout -> B-operand transform (R4-verified exchange, packed pairs:
      // bf16-convert commutes with permute; low half = tile0, high = tile1)
      short8 bp;
      #pragma unroll
      for (int r = 0; r < 4; ++r) {
        const uint32_t pe = pk2(e0[r], e1[r]);
        const int lo = __builtin_amdgcn_ds_bpermute(alo, (int)pe);
        const int hi = __builtin_amdgcn_ds_bpermute(alo + 64, (int)pe);
        bp[r]     = (short)(uint16_t)(hiTile ? (lo >> 16) : (lo & 0xFFFF));
        bp[4 + r] = (short)(uint16_t)(hiTile ? (hi >> 16) : (hi & 0xFFFF));
      }

      // PV: A=V (m=d), B=P (n=p) -> D row=d col=p
      #pragma unroll
      for (int dt = 0; dt < 8; ++dt)
        acc[bb][dt] = __builtin_amdgcn_mfma_f32_16x16x32_bf16(av[dt], bp, acc[bb][dt], 0, 0, 0);
    }
  }

  // --- row-sum reduce (per batch) and publish ---
  #pragma unroll
  for (int bb = 0; bb < 2; ++bb) {
    float sv = Ssum[bb];
    sv += __shfl_xor(sv, 16);
    sv += __shfl_xor(sv, 32);
    if (lane < 16) sS[bb][w][lane] = sv;
  }
  __syncthreads();
  const float inv0 = 1.f / (sS[0][0][ln] + sS[0][1][ln] + sS[0][2][ln] + sS[0][3][ln]);
  const float inv1 = 1.f / (sS[1][0][ln] + sS[1][1][ln] + sS[1][2][ln] + sS[1][3][ln]);
  const int pp = p0 + ln;

  // --- merge across 4 j-split waves: 4 rounds of 4 d-tiles ---
  for (int rd = 0; rd < 4; ++rd) {
    const int bb = rd >> 1, hf = rd & 1;
    #pragma unroll
    for (int g = 0; g < 4; ++g)
      *(floatx4*)&mergeAcc[g][w][lane * 4] = acc[bb][hf * 4 + g];
    __syncthreads();
    floatx4 v = *(const floatx4*)&mergeAcc[w][0][lane * 4];
    v += *(const floatx4*)&mergeAcc[w][1][lane * 4];
    v += *(const floatx4*)&mergeAcc[w][2][lane * 4];
    v += *(const floatx4*)&mergeAcc[w][3][lane * 4];
    if (pp < NP) {
      const float inv = bb ? inv1 : inv0;
      const int dtile = hf * 4 + w;                // this wave's merged d-tile
      float* ob = out + ((size_t)((b0 + bb) * KCLS + kc) * ND + dtile * 16 + q * 4) * NP + pp;
      #pragma unroll
      for (int rr = 0; rr < 4; ++rr) ob[(size_t)rr * NP] = v[rr] * inv;
    }
    __syncthreads();
  }
}

// ---------------------------------------------------------------------------
extern "C" void kernel_launch(void* const* d_in, const int* in_sizes, int n_in,
                              void* d_out, int out_size, void* d_ws, size_t ws_size,
                              hipStream_t stream) {
  const float* supp   = (const float*)d_in[0];
  const float* qry    = (const float*)d_in[1];
  const int*   labels = (const int*)d_in[2];
  const float* Wqk    = (const float*)d_in[3];
  const float* Wv     = (const float*)d_in[4];
  float* out = (float*)d_out;

  // ws layout (~28 MB)
  uint16_t* Xhi = (uint16_t*)d_ws;
  uint16_t* Xlo = Xhi + (size_t)NIMG * JS * NC;
  uint16_t* Whi = Xlo + (size_t)NIMG * JS * NC;
  uint16_t* Wlo = Whi + (size_t)2 * ND * NC;
  uint16_t* Qt  = Wlo + (size_t)2 * ND * NC;        // [32][196][128]
  uint16_t* Kt  = Qt  + (size_t)NB * NP * ND;       // [25][208][128]
  uint16_t* Vt  = Kt  + (size_t)NSUP * JS * ND;     // [25][128][208]
  float* outVq = out + (size_t)NB * KCLS * ND * NP; // query_v_flat region

  conv_kernel<<<914, 256, 0, stream>>>(supp, qry, Wqk, Wv, Xhi, Xlo, Whi, Wlo);
  gemm_kernel<<<1482, 64, 0, stream>>>(Xhi, Xlo, Whi, Wlo, Qt, Kt, Vt, outVq);
  attn_kernel<<<1040, 256, 0, stream>>>(Qt, Kt, Vt, labels, out);
}